// Round 12
// baseline (5699.792 us; speedup 1.0000x reference)
//
#include <hip/hip_runtime.h>
#include <math.h>

#define VOCAB  32000
#define EMBED  512
#define HIDDEN 1024
#define BATCH  16
#define SEQ    256
#define M_TOTAL (BATCH*SEQ)   // 4096
#define RNN_BLOCKS 64
#define COLS 16               // columns per RNN block
#define NFLAGS ((SEQ-1)*RNN_BLOCKS)
#define RSTRIDE 1028          // padded LDS row (floats)

typedef __attribute__((ext_vector_type(8))) short short8;
typedef __attribute__((ext_vector_type(4))) float f32x4;

static __device__ __forceinline__ unsigned short f2bf(float x) {
    unsigned int u = __float_as_uint(x);
    unsigned int r = (u + 0x7FFFu + ((u >> 16) & 1u)) >> 16;   // RNE
    return (unsigned short)r;
}
static __device__ __forceinline__ float bf2f(unsigned short b) {
    return __uint_as_float(((unsigned int)b) << 16);
}

// --------------------------------------------------------- zero flag array
__global__ __launch_bounds__(256) void k_zero(int* __restrict__ flags) {
    const int i = blockIdx.x * 256 + threadIdx.x;
    if (i < NFLAGS) flags[i] = 0;
}

// ------------------------------------------------- K1: embed + xproj GEMM
__global__ __launch_bounds__(256) void k_embed_xproj(
    const int* __restrict__ tok, const float* __restrict__ emb,
    const float* __restrict__ Wxh, const float* __restrict__ bias,
    float* __restrict__ xproj)
{
    __shared__ float At[16][68];
    __shared__ float Bt[16][68];
    const int row0 = blockIdx.y * 64;
    const int col0 = blockIdx.x * 64;
    const int tid = threadIdx.x;
    const int tx = tid & 15, ty = tid >> 4;

    const int am = tid >> 2, aq = tid & 3;
    const int bn = tid & 15, bk = tid >> 4;

    const int tokid = tok[row0 + am];
    const float4* embrow = (tokid == 0) ? (const float4*)nullptr
                         : (const float4*)(emb + (size_t)tokid * EMBED);

    float acc[4][4] = {};

    for (int k0 = 0; k0 < EMBED; k0 += 16) {
        float4 av = make_float4(0.f, 0.f, 0.f, 0.f);
        if (embrow) av = embrow[(k0 >> 2) + aq];
        float4 bv = *(const float4*)(Wxh + (size_t)(k0 + bk) * HIDDEN + col0 + bn * 4);

        __syncthreads();
        At[aq*4+0][am] = av.x; At[aq*4+1][am] = av.y;
        At[aq*4+2][am] = av.z; At[aq*4+3][am] = av.w;
        *(float4*)&Bt[bk][bn*4] = bv;
        __syncthreads();

        #pragma unroll
        for (int k = 0; k < 16; ++k) {
            float4 a = *(const float4*)&At[k][ty*4];
            float4 b = *(const float4*)&Bt[k][tx*4];
            float aa[4] = {a.x, a.y, a.z, a.w};
            float bb[4] = {b.x, b.y, b.z, b.w};
            #pragma unroll
            for (int i = 0; i < 4; ++i)
                #pragma unroll
                for (int j = 0; j < 4; ++j)
                    acc[i][j] = fmaf(aa[i], bb[j], acc[i][j]);
        }
    }

    float4 bb = *(const float4*)(bias + col0 + tx*4);
    #pragma unroll
    for (int i = 0; i < 4; ++i) {
        const int row = row0 + ty*4 + i;
        float4 v = make_float4(acc[i][0] + bb.x, acc[i][1] + bb.y,
                               acc[i][2] + bb.z, acc[i][3] + bb.w);
        *(float4*)(xproj + (size_t)row * HIDDEN + col0 + tx*4) = v;
    }
}

// ------------------------------------------------- K2: persistent RNN scan
// r6 structure (256 thr, 2.05 ms validated) + weights promoted to VGPRs:
// thread (b4,c4,ks) owns wreg[4][16] f32x4 = 256 VGPRs (4 cols x 64 k),
// statically indexed (rule #20). 256 thr = 4 waves = 1 wave/SIMD -> VGPR
// budget ~450+ (m08); r11 proved 512-thr blocks cap at 112 and spill.
// Inner loop reads ONLY h from LDS (halves LDS traffic vs r6).
// Sync protocol byte-identical to r6 (4x validated).
__global__ __launch_bounds__(256, 1) void k_rnn(
    const float* __restrict__ xproj, const float* __restrict__ Whh,
    float* __restrict__ hs, int* __restrict__ flags)
{
    __shared__ float smem[COLS * RSTRIDE];   // w-stage (once), then h[t-1]
    const int bid = blockIdx.x;
    const int tid = threadIdx.x;
    const int ks  = tid & 15;                // k-segment (64 k's)
    const int bc  = tid >> 4;
    const int b4  = bc >> 2;                 // batch quad
    const int c4  = bc & 3;                  // col quad
    const int lane = tid & 63;

    // ---- stage Whh[:, bid*16..+16) into LDS (swizzled, r6 layout), once
    {
        const int c = tid & 15, kk = tid >> 4;
        for (int i = 0; i < 64; ++i) {
            const int k = kk + (i << 4);
            const float v = Whh[(size_t)k * HIDDEN + bid * COLS + c];
            const int s = k >> 2, e = k & 3;
            const int sw = s ^ ((s >> 4) & 15);
            smem[c * RSTRIDE + sw * 4 + e] = v;
        }
    }
    __syncthreads();

    // ---- pull this thread's 4-col x 64-k weight tile into VGPRs.
    // Same index function the r6 inner loop used for its w reads.
    const int ks16 = ks * 16;
    f32x4 wreg[4][16];
    #pragma unroll
    for (int j = 0; j < 4; ++j)
        #pragma unroll
        for (int kq = 0; kq < 16; ++kq) {
            const int sp = ((ks16 + kq) ^ ks) * 4;
            wreg[j][kq] = *(const f32x4*)&smem[(c4 * 4 + j) * RSTRIDE + sp];
        }
    __syncthreads();                          // smem now free for h staging

    const int ob = b4 * 4 + (ks >> 2);        // this thread's output (b, c)
    const int oc = c4 * 4 + (ks & 3);
    const int cg = bid * COLS + oc;

    float xp_pref = xproj[((size_t)ob * SEQ + 0) * HIDDEN + cg];

    for (int t = 0; t < SEQ; ++t) {
        const float xp = xp_pref;
        if (t + 1 < SEQ)
            xp_pref = xproj[((size_t)ob * SEQ + (t + 1)) * HIDDEN + cg];

        float acc[4][4] = {};
        if (t > 0) {
            // ---- stage h[t-1]: 16 bypass loads in flight, one drain (r6)
            f32x4 tmp[BATCH];
            #pragma unroll
            for (int bb = 0; bb < BATCH; ++bb) {
                const float* p = hs + ((size_t)bb * SEQ + (t - 1)) * HIDDEN + tid * 4;
                asm volatile("global_load_dwordx4 %0, %1, off sc0 sc1"
                             : "=&v"(tmp[bb]) : "v"(p));
            }
            asm volatile("s_waitcnt vmcnt(0)" ::: "memory");
            const int swf = (tid ^ ((tid >> 4) & 15)) * 4;
            #pragma unroll
            for (int bb = 0; bb < BATCH; ++bb)
                *(f32x4*)&smem[bb * RSTRIDE + swf] = tmp[bb];
            __syncthreads();

            // ---- compute: 16 k-quads, h from LDS, w from VGPRs (static idx)
            #pragma unroll
            for (int kq = 0; kq < 16; ++kq) {
                const int sp = ((ks16 + kq) ^ ks) * 4;
                float4 h4[4];
                #pragma unroll
                for (int i = 0; i < 4; ++i)
                    h4[i] = *(const float4*)&smem[(b4*4 + i) * RSTRIDE + sp];
                #pragma unroll
                for (int i = 0; i < 4; ++i)
                    #pragma unroll
                    for (int j = 0; j < 4; ++j) {
                        const f32x4 w = wreg[j][kq];
                        acc[i][j] = fmaf(h4[i].x, w[0], acc[i][j]);
                        acc[i][j] = fmaf(h4[i].y, w[1], acc[i][j]);
                        acc[i][j] = fmaf(h4[i].z, w[2], acc[i][j]);
                        acc[i][j] = fmaf(h4[i].w, w[3], acc[i][j]);
                    }
            }
        }
        // butterfly reduce across the 16 ks-lanes
        #pragma unroll
        for (int off = 8; off >= 1; off >>= 1)
            #pragma unroll
            for (int i = 0; i < 4; ++i)
                #pragma unroll
                for (int j = 0; j < 4; ++j)
                    acc[i][j] += __shfl_xor(acc[i][j], off, 16);

        const float val = tanhf(xp + acc[ks >> 2][ks & 3]);
        __hip_atomic_store(hs + ((size_t)ob * SEQ + t) * HIDDEN + cg, val,
                           __ATOMIC_RELAXED, __HIP_MEMORY_SCOPE_SYSTEM);

        if (t < SEQ - 1) {
            asm volatile("s_waitcnt vmcnt(0)" ::: "memory");  // h at L3
            __syncthreads();
            if (tid == 0)
                __hip_atomic_store(&flags[t * RNN_BLOCKS + bid], 1,
                                   __ATOMIC_RELEASE, __HIP_MEMORY_SCOPE_AGENT);
            // wave-wide poll: lane i watches block i (acquire invalidates)
            while (__hip_atomic_load(&flags[t * RNN_BLOCKS + lane],
                                     __ATOMIC_ACQUIRE, __HIP_MEMORY_SCOPE_AGENT) == 0)
                __builtin_amdgcn_s_sleep(4);
            __syncthreads();
        }
    }
}

// --------------------------------------------- hi/lo bf16 split: hs (no T)
__global__ __launch_bounds__(256) void k_cvt_hs(
    const float* __restrict__ src, unsigned short* __restrict__ h,
    unsigned short* __restrict__ l)
{
    const size_t i = ((size_t)blockIdx.x * 256 + threadIdx.x) * 4;
    const float4 v = *(const float4*)(src + i);
    float f[4] = {v.x, v.y, v.z, v.w};
    unsigned short hh[4], ll[4];
    #pragma unroll
    for (int e = 0; e < 4; ++e) {
        hh[e] = f2bf(f[e]);
        ll[e] = f2bf(f[e] - bf2f(hh[e]));
    }
    *(ushort4*)(h + i) = make_ushort4(hh[0], hh[1], hh[2], hh[3]);
    *(ushort4*)(l + i) = make_ushort4(ll[0], ll[1], ll[2], ll[3]);
}

// ------------------------------- hi/lo bf16 split + transpose: Wout -> [n][k]
__global__ __launch_bounds__(256) void k_cvt_wT(
    const float* __restrict__ W, unsigned short* __restrict__ WTh,
    unsigned short* __restrict__ WTl)
{
    __shared__ float t[64][68];
    const int n0 = blockIdx.x * 64, k0 = blockIdx.y * 64;
    const int tid = threadIdx.x;
    const int r = tid >> 4, c4 = tid & 15;
    #pragma unroll
    for (int p = 0; p < 4; ++p) {
        const float4 v = *(const float4*)(W + (size_t)(k0 + r + p*16) * VOCAB + n0 + c4*4);
        *(float4*)&t[r + p*16][c4*4] = v;
    }
    __syncthreads();
    #pragma unroll
    for (int p = 0; p < 4; ++p) {
        const int rn = r + p * 16;                 // local n
        unsigned short hh[4], ll[4];
        #pragma unroll
        for (int j = 0; j < 4; ++j) {
            const float x = t[c4*4 + j][rn];       // W[k][n]
            hh[j] = f2bf(x);
            ll[j] = f2bf(x - bf2f(hh[j]));
        }
        const size_t o = (size_t)(n0 + rn) * HIDDEN + k0 + c4*4;
        *(ushort4*)(WTh + o) = make_ushort4(hh[0], hh[1], hh[2], hh[3]);
        *(ushort4*)(WTl + o) = make_ushort4(ll[0], ll[1], ll[2], ll[3]);
    }
}

// --------------------------------------- K3: logits GEMM, split-bf16 MFMA
__global__ __launch_bounds__(256) void k_logits_mfma(
    const unsigned short* __restrict__ Ahp, const unsigned short* __restrict__ Alp,
    const unsigned short* __restrict__ Bhp, const unsigned short* __restrict__ Blp,
    const float* __restrict__ bout, float* __restrict__ out)
{
    __shared__ unsigned short sAh[128*32], sAl[128*32], sBh[128*32], sBl[128*32];
    const int bid0 = blockIdx.x;
    const int sid = (bid0 & 7) * (8000 / 8) + (bid0 >> 3);   // XCD-chunked
    const int n0 = (sid >> 5) * 128;       // 250 n-panels
    const int m0 = (sid & 31) * 128;       // 32 m-panels (consecutive share B)
    const int tid = threadIdx.x;
    const int wv = tid >> 6, l = tid & 63;
    const int wr = wv >> 1, wc = wv & 1;
    const int rr = l & 15, kb = l >> 4;

    f32x4 acc[4][4];
    #pragma unroll
    for (int i = 0; i < 4; ++i)
        #pragma unroll
        for (int j = 0; j < 4; ++j) acc[i][j] = (f32x4)0.f;

    const int sr = tid >> 2, q = tid & 3;

    for (int kt = 0; kt < 32; ++kt) {
        const int k0 = kt * 32;
        __syncthreads();
        #pragma unroll
        for (int p = 0; p < 2; ++p) {
            const int r = sr + p * 64;
            const int ws = (q ^ ((r >> 1) & 3)) << 3;       // ushort offset
            const size_t ga = (size_t)(m0 + r) * HIDDEN + k0 + q * 8;
            const size_t gb = (size_t)(n0 + r) * HIDDEN + k0 + q * 8;
            *(short8*)&sAh[r*32 + ws] = *(const short8*)(Ahp + ga);
            *(short8*)&sAl[r*32 + ws] = *(const short8*)(Alp + ga);
            *(short8*)&sBh[r*32 + ws] = *(const short8*)(Bhp + gb);
            *(short8*)&sBl[r*32 + ws] = *(const short8*)(Blp + gb);
        }
        __syncthreads();

        short8 fah[4], fal[4], fbh[4], fbl[4];
        #pragma unroll
        for (int i = 0; i < 4; ++i) {
            const int ra = wr*64 + i*16 + rr;
            const int sa = ra*32 + ((kb ^ ((ra >> 1) & 3)) << 3);
            fah[i] = *(const short8*)&sAh[sa];
            fal[i] = *(const short8*)&sAl[sa];
            const int rb = wc*64 + i*16 + rr;
            const int sb = rb*32 + ((kb ^ ((rb >> 1) & 3)) << 3);
            fbh[i] = *(const short8*)&sBh[sb];
            fbl[i] = *(const short8*)&sBl[sb];
        }
        #pragma unroll
        for (int i = 0; i < 4; ++i)
            #pragma unroll
            for (int j = 0; j < 4; ++j) {
                acc[i][j] = __builtin_amdgcn_mfma_f32_16x16x32_bf16(fah[i], fbh[j], acc[i][j], 0, 0, 0);
                acc[i][j] = __builtin_amdgcn_mfma_f32_16x16x32_bf16(fah[i], fbl[j], acc[i][j], 0, 0, 0);
                acc[i][j] = __builtin_amdgcn_mfma_f32_16x16x32_bf16(fal[i], fbh[j], acc[i][j], 0, 0, 0);
            }
    }

    #pragma unroll
    for (int j = 0; j < 4; ++j) {
        const int col = n0 + wc*64 + j*16 + rr;
        const float bj = bout[col];
        #pragma unroll
        for (int i = 0; i < 4; ++i) {
            const int row0 = m0 + wr*64 + i*16 + kb*4;
            #pragma unroll
            for (int p = 0; p < 4; ++p)
                out[(size_t)(row0 + p) * VOCAB + col] = acc[i][j][p] + bj;
        }
    }
}

// ------------------------------------------------- fallback f32 logits GEMM
__global__ __launch_bounds__(256) void k_logits(
    const float* __restrict__ hs, const float* __restrict__ Wout,
    const float* __restrict__ bout, float* __restrict__ out)
{
    __shared__ float At[16][132];
    __shared__ float Bt[16][132];
    const int col0 = blockIdx.x * 128;
    const int row0 = blockIdx.y * 128;
    const int tid = threadIdx.x;
    const int tx = tid & 15, ty = tid >> 4;

    float acc[8][8] = {};

    for (int k0 = 0; k0 < HIDDEN; k0 += 16) {
        float4 av[2], bv[2];
        #pragma unroll
        for (int p = 0; p < 2; ++p) {
            const int idx = tid + p * 256;
            const int m = idx >> 2, qq = idx & 3;
            av[p] = *(const float4*)(hs + (size_t)(row0 + m) * HIDDEN + k0 + qq * 4);
            const int n4 = idx & 31, kk = idx >> 5;
            bv[p] = *(const float4*)(Wout + (size_t)(k0 + kk) * VOCAB + col0 + n4 * 4);
        }
        __syncthreads();
        #pragma unroll
        for (int p = 0; p < 2; ++p) {
            const int idx = tid + p * 256;
            const int m = idx >> 2, qq = idx & 3;
            At[qq*4+0][m] = av[p].x; At[qq*4+1][m] = av[p].y;
            At[qq*4+2][m] = av[p].z; At[qq*4+3][m] = av[p].w;
            const int n4 = idx & 31, kk = idx >> 5;
            *(float4*)&Bt[kk][n4*4] = bv[p];
        }
        __syncthreads();

        #pragma unroll
        for (int k = 0; k < 16; ++k) {
            float a[8], b[8];
            *(float4*)&a[0] = *(const float4*)&At[k][ty*4];
            *(float4*)&a[4] = *(const float4*)&At[k][64 + ty*4];
            *(float4*)&b[0] = *(const float4*)&Bt[k][tx*4];
            *(float4*)&b[4] = *(const float4*)&Bt[k][64 + tx*4];
            #pragma unroll
            for (int i = 0; i < 8; ++i)
                #pragma unroll
                for (int j = 0; j < 8; ++j)
                    acc[i][j] = fmaf(a[i], b[j], acc[i][j]);
        }
    }

    const float4 blo = *(const float4*)(bout + col0 + tx*4);
    const float4 bhi = *(const float4*)(bout + col0 + 64 + tx*4);
    #pragma unroll
    for (int ih = 0; ih < 2; ++ih)
        #pragma unroll
        for (int i = 0; i < 4; ++i) {
            const int row = row0 + ih*64 + ty*4 + i;
            float* orow = out + (size_t)row * VOCAB + col0;
            const int r = ih*4 + i;
            float4 v0 = make_float4(acc[r][0] + blo.x, acc[r][1] + blo.y,
                                    acc[r][2] + blo.z, acc[r][3] + blo.w);
            float4 v1 = make_float4(acc[r][4] + bhi.x, acc[r][5] + bhi.y,
                                    acc[r][6] + bhi.z, acc[r][7] + bhi.w);
            *(float4*)(orow + tx*4) = v0;
            *(float4*)(orow + 64 + tx*4) = v1;
        }
}

// ----------------------------------------------------------------- launch
extern "C" void kernel_launch(void* const* d_in, const int* in_sizes, int n_in,
                              void* d_out, int out_size, void* d_ws, size_t ws_size,
                              hipStream_t stream) {
    const int*   tok  = (const int*)d_in[0];
    const float* emb  = (const float*)d_in[1];
    const float* Wxh  = (const float*)d_in[2];
    const float* Whh  = (const float*)d_in[3];
    const float* bias = (const float*)d_in[4];
    const float* Wout = (const float*)d_in[5];
    const float* bout = (const float*)d_in[6];
    float* out = (float*)d_out;

    char* ws = (char*)d_ws;
    int* flags = (int*)ws;

    // layout (bytes); first 64 KB = flag region
    const size_t OFF_HS   = 65536;
    const size_t OFF_HSH  = OFF_HS  + (size_t)M_TOTAL * HIDDEN * 4;
    const size_t OFF_HSL  = OFF_HSH + (size_t)M_TOTAL * HIDDEN * 2;
    const size_t OFF_WTH  = OFF_HSL + (size_t)M_TOTAL * HIDDEN * 2;
    const size_t OFF_WTL  = OFF_WTH + (size_t)VOCAB * HIDDEN * 2;
    const size_t OFF_XP   = OFF_WTL + (size_t)VOCAB * HIDDEN * 2;
    const size_t NEED     = OFF_XP  + (size_t)M_TOTAL * HIDDEN * 4;

    if (ws_size >= NEED) {
        float*          hs   = (float*)(ws + OFF_HS);
        unsigned short* hsh  = (unsigned short*)(ws + OFF_HSH);
        unsigned short* hsl  = (unsigned short*)(ws + OFF_HSL);
        unsigned short* wth  = (unsigned short*)(ws + OFF_WTH);
        unsigned short* wtl  = (unsigned short*)(ws + OFF_WTL);
        float*          xproj= (float*)(ws + OFF_XP);

        hipLaunchKernelGGL(k_zero, dim3(64), dim3(256), 0, stream, flags);
        hipLaunchKernelGGL(k_embed_xproj, dim3(HIDDEN/64, M_TOTAL/64), dim3(256), 0, stream,
                           tok, emb, Wxh, bias, xproj);
        hipLaunchKernelGGL(k_rnn, dim3(RNN_BLOCKS), dim3(256), 0, stream,
                           xproj, Whh, hs, flags);
        hipLaunchKernelGGL(k_cvt_hs, dim3(M_TOTAL*HIDDEN/1024), dim3(256), 0, stream,
                           hs, hsh, hsl);
        hipLaunchKernelGGL(k_cvt_wT, dim3(VOCAB/64, HIDDEN/64), dim3(256), 0, stream,
                           Wout, wth, wtl);
        hipLaunchKernelGGL(k_logits_mfma, dim3((VOCAB/128)*(M_TOTAL/128)), dim3(256), 0, stream,
                           hsh, hsl, wth, wtl, bout, out);
    } else {
        // fallback: f32 logits path (fits in ~33 MB)
        float* xproj = (float*)(ws + 65536);
        float* hs    = (float*)(ws + 65536 + (size_t)M_TOTAL * HIDDEN * 4);

        hipLaunchKernelGGL(k_zero, dim3(64), dim3(256), 0, stream, flags);
        hipLaunchKernelGGL(k_embed_xproj, dim3(HIDDEN/64, M_TOTAL/64), dim3(256), 0, stream,
                           tok, emb, Wxh, bias, xproj);
        hipLaunchKernelGGL(k_rnn, dim3(RNN_BLOCKS), dim3(256), 0, stream,
                           xproj, Whh, hs, flags);
        hipLaunchKernelGGL(k_logits, dim3(VOCAB/128, M_TOTAL/128), dim3(256), 0, stream,
                           hs, Wout, bout, out);
    }
}

// Round 14
// 3085.134 us; speedup vs baseline: 1.8475x; 1.8475x over previous
//
#include <hip/hip_runtime.h>
#include <math.h>

#define VOCAB  32000
#define EMBED  512
#define HIDDEN 1024
#define BATCH  16
#define SEQ    256
#define M_TOTAL (BATCH*SEQ)   // 4096
#define RNN_BLOCKS 64
#define CONVBLKS 192          // Wout-conversion blocks fused into k_rnn launch
#define COLS 16               // columns per RNN block
#define NFLAGS ((SEQ-1)*RNN_BLOCKS)
#define RSTRIDE 1028          // padded LDS row (floats)

typedef __attribute__((ext_vector_type(8))) short short8;
typedef __attribute__((ext_vector_type(4))) float f32x4;

static __device__ __forceinline__ unsigned short f2bf(float x) {
    unsigned int u = __float_as_uint(x);
    unsigned int r = (u + 0x7FFFu + ((u >> 16) & 1u)) >> 16;   // RNE
    return (unsigned short)r;
}
static __device__ __forceinline__ float bf2f(unsigned short b) {
    return __uint_as_float(((unsigned int)b) << 16);
}

// --------------------------------------------------------- zero flag array
__global__ __launch_bounds__(256) void k_zero(int* __restrict__ flags) {
    const int i = blockIdx.x * 256 + threadIdx.x;
    if (i < NFLAGS) flags[i] = 0;
}

// ------------------------------------------------- K1: embed + xproj GEMM
__global__ __launch_bounds__(256) void k_embed_xproj(
    const int* __restrict__ tok, const float* __restrict__ emb,
    const float* __restrict__ Wxh, const float* __restrict__ bias,
    float* __restrict__ xproj)
{
    __shared__ float At[16][68];
    __shared__ float Bt[16][68];
    const int row0 = blockIdx.y * 64;
    const int col0 = blockIdx.x * 64;
    const int tid = threadIdx.x;
    const int tx = tid & 15, ty = tid >> 4;

    const int am = tid >> 2, aq = tid & 3;
    const int bn = tid & 15, bk = tid >> 4;

    const int tokid = tok[row0 + am];
    const float4* embrow = (tokid == 0) ? (const float4*)nullptr
                         : (const float4*)(emb + (size_t)tokid * EMBED);

    float acc[4][4] = {};

    for (int k0 = 0; k0 < EMBED; k0 += 16) {
        float4 av = make_float4(0.f, 0.f, 0.f, 0.f);
        if (embrow) av = embrow[(k0 >> 2) + aq];
        float4 bv = *(const float4*)(Wxh + (size_t)(k0 + bk) * HIDDEN + col0 + bn * 4);

        __syncthreads();
        At[aq*4+0][am] = av.x; At[aq*4+1][am] = av.y;
        At[aq*4+2][am] = av.z; At[aq*4+3][am] = av.w;
        *(float4*)&Bt[bk][bn*4] = bv;
        __syncthreads();

        #pragma unroll
        for (int k = 0; k < 16; ++k) {
            float4 a = *(const float4*)&At[k][ty*4];
            float4 b = *(const float4*)&Bt[k][tx*4];
            float aa[4] = {a.x, a.y, a.z, a.w};
            float bb[4] = {b.x, b.y, b.z, b.w};
            #pragma unroll
            for (int i = 0; i < 4; ++i)
                #pragma unroll
                for (int j = 0; j < 4; ++j)
                    acc[i][j] = fmaf(aa[i], bb[j], acc[i][j]);
        }
    }

    float4 bb = *(const float4*)(bias + col0 + tx*4);
    #pragma unroll
    for (int i = 0; i < 4; ++i) {
        const int row = row0 + ty*4 + i;
        float4 v = make_float4(acc[i][0] + bb.x, acc[i][1] + bb.y,
                               acc[i][2] + bb.z, acc[i][3] + bb.w);
        *(float4*)(xproj + (size_t)row * HIDDEN + col0 + tx*4) = v;
    }
}

// ---------------------------- K2: persistent RNN scan + fused Wout convert
// Blocks 0..63: EXACT round-6 scan (2.05 ms, validated 3x): thread (b4,c4,ks)
// does 4x4 partials over 64 k's, w+h in LDS, bypass h-stores, flag barrier
// (SYSTEM relaxed store / SYSTEM relaxed poll, s_sleep backoff). Added only:
// writer also emits the bf16 hi/lo split of val (deletes k_cvt_hs pass).
// Blocks 64..255: grid-stride Wout transpose+split (the old k_cvt_wT),
// running on CUs the scan leaves idle. No shared state with scan blocks;
// worst-case dispatch order just serializes them (old behavior).
__global__ __launch_bounds__(256) void k_rnn(
    const float* __restrict__ xproj, const float* __restrict__ Whh,
    float* __restrict__ hs, int* __restrict__ flags,
    unsigned short* __restrict__ hsh, unsigned short* __restrict__ hsl,
    const float* __restrict__ Wout,
    unsigned short* __restrict__ wth, unsigned short* __restrict__ wtl)
{
    __shared__ float wl[COLS * RSTRIDE];    // [c][k] swizzled (scan) / conv tile
    __shared__ float hl[BATCH * RSTRIDE];   // [b][k] swizzled (scan)
    const int bid = blockIdx.x;
    const int tid = threadIdx.x;

    if (bid >= RNN_BLOCKS) {
        // ---------------- conv path: Wout -> [n][k] bf16 hi/lo ----------------
        const int cb = bid - RNN_BLOCKS;
        float (*tt)[68] = (float(*)[68])wl;
        const int r = tid >> 4, cc = tid & 15;
        for (int p = cb; p < (VOCAB/64) * (HIDDEN/64); p += CONVBLKS) {
            const int n0 = (p % (VOCAB/64)) * 64;
            const int k0 = (p / (VOCAB/64)) * 64;
            #pragma unroll
            for (int q = 0; q < 4; ++q) {
                const float4 v = *(const float4*)(Wout +
                    (size_t)(k0 + r + q*16) * VOCAB + n0 + cc*4);
                *(float4*)&tt[r + q*16][cc*4] = v;
            }
            __syncthreads();
            #pragma unroll
            for (int q = 0; q < 4; ++q) {
                const int rn = r + q * 16;             // local n
                unsigned short hh4[4], ll4[4];
                #pragma unroll
                for (int j = 0; j < 4; ++j) {
                    const float x = tt[cc*4 + j][rn];  // W[k][n]
                    hh4[j] = f2bf(x);
                    ll4[j] = f2bf(x - bf2f(hh4[j]));
                }
                const size_t o = (size_t)(n0 + rn) * HIDDEN + k0 + cc*4;
                *(ushort4*)(wth + o) = make_ushort4(hh4[0], hh4[1], hh4[2], hh4[3]);
                *(ushort4*)(wtl + o) = make_ushort4(ll4[0], ll4[1], ll4[2], ll4[3]);
            }
            __syncthreads();
        }
        return;
    }

    // ---------------- scan path (round-6 verbatim + hi/lo store) ----------------
    const int ks  = tid & 15;
    const int bc  = tid >> 4;
    const int b4  = bc >> 2;
    const int c4  = bc & 3;
    const int lane = tid & 63;

    // stage Whh[:, bid*16..+16) into wl (transposed + swizzled), once
    {
        const int c = tid & 15, kk = tid >> 4;
        for (int i = 0; i < 64; ++i) {
            const int k = kk + (i << 4);
            const float v = Whh[(size_t)k * HIDDEN + bid * COLS + c];
            const int s = k >> 2, e = k & 3;
            const int sw = s ^ ((s >> 4) & 15);
            wl[c * RSTRIDE + sw * 4 + e] = v;
        }
    }
    __syncthreads();

    const int ob = b4 * 4 + (ks >> 2);      // this thread's output (b, c)
    const int oc = c4 * 4 + (ks & 3);
    const int cg = bid * COLS + oc;

    for (int t = 0; t < SEQ; ++t) {
        const float xp = xproj[((size_t)ob * SEQ + t) * HIDDEN + cg];

        float acc[4][4] = {};
        if (t > 0) {
            // stage h[t-1]: 16 bypass loads in flight, then one drain
            f32x4 tmp[BATCH];
            #pragma unroll
            for (int bb = 0; bb < BATCH; ++bb) {
                const float* p = hs + ((size_t)bb * SEQ + (t - 1)) * HIDDEN + tid * 4;
                asm volatile("global_load_dwordx4 %0, %1, off sc0 sc1"
                             : "=&v"(tmp[bb]) : "v"(p));
            }
            asm volatile("s_waitcnt vmcnt(0)" ::: "memory");
            const int swf = (tid ^ ((tid >> 4) & 15)) * 4;
            #pragma unroll
            for (int bb = 0; bb < BATCH; ++bb)
                *(f32x4*)&hl[bb * RSTRIDE + swf] = tmp[bb];
            __syncthreads();
            const int ks16 = ks * 16;
            #pragma unroll 4
            for (int kq = 0; kq < 16; ++kq) {
                const int sp = ((ks16 + kq) ^ ks) * 4;
                float4 h4[4], w4[4];
                #pragma unroll
                for (int i = 0; i < 4; ++i)
                    h4[i] = *(const float4*)&hl[(b4*4 + i) * RSTRIDE + sp];
                #pragma unroll
                for (int j = 0; j < 4; ++j)
                    w4[j] = *(const float4*)&wl[(c4*4 + j) * RSTRIDE + sp];
                #pragma unroll
                for (int i = 0; i < 4; ++i)
                    #pragma unroll
                    for (int j = 0; j < 4; ++j) {
                        acc[i][j] = fmaf(h4[i].x, w4[j].x, acc[i][j]);
                        acc[i][j] = fmaf(h4[i].y, w4[j].y, acc[i][j]);
                        acc[i][j] = fmaf(h4[i].z, w4[j].z, acc[i][j]);
                        acc[i][j] = fmaf(h4[i].w, w4[j].w, acc[i][j]);
                    }
            }
        }
        // butterfly reduce across the 16 ks-lanes
        #pragma unroll
        for (int off = 8; off >= 1; off >>= 1)
            #pragma unroll
            for (int i = 0; i < 4; ++i)
                #pragma unroll
                for (int j = 0; j < 4; ++j)
                    acc[i][j] += __shfl_xor(acc[i][j], off, 16);

        const float val = tanhf(xp + acc[ks >> 2][ks & 3]);
        const size_t orow = ((size_t)ob * SEQ + t) * HIDDEN + cg;
        // bypass store: completes at L3; flag release below publishes it
        __hip_atomic_store(hs + orow, val,
                           __ATOMIC_RELAXED, __HIP_MEMORY_SCOPE_SYSTEM);
        if (hsh) {       // fused hi/lo split (replaces k_cvt_hs pass)
            const unsigned short hi = f2bf(val);
            hsh[orow] = hi;
            hsl[orow] = f2bf(val - bf2f(hi));
        }

        if (t < SEQ - 1) {
            asm volatile("s_waitcnt vmcnt(0)" ::: "memory");  // h at L3
            __syncthreads();
            if (tid == 0)
                __hip_atomic_store(&flags[t * RNN_BLOCKS + bid], 1,
                                   __ATOMIC_RELAXED, __HIP_MEMORY_SCOPE_SYSTEM);
            // wave-wide poll: lane i watches block i's flag
            while (__hip_atomic_load(&flags[t * RNN_BLOCKS + lane],
                                     __ATOMIC_RELAXED, __HIP_MEMORY_SCOPE_SYSTEM) == 0)
                __builtin_amdgcn_s_sleep(1);
            __syncthreads();
        }
    }
}

// --------------------------------------- K3: logits GEMM, split-bf16 MFMA
__global__ __launch_bounds__(256) void k_logits_mfma(
    const unsigned short* __restrict__ Ahp, const unsigned short* __restrict__ Alp,
    const unsigned short* __restrict__ Bhp, const unsigned short* __restrict__ Blp,
    const float* __restrict__ bout, float* __restrict__ out)
{
    __shared__ unsigned short sAh[128*32], sAl[128*32], sBh[128*32], sBl[128*32];
    const int bid0 = blockIdx.x;
    const int sid = (bid0 & 7) * (8000 / 8) + (bid0 >> 3);   // XCD-chunked
    const int n0 = (sid >> 5) * 128;       // 250 n-panels
    const int m0 = (sid & 31) * 128;       // 32 m-panels (consecutive share B)
    const int tid = threadIdx.x;
    const int wv = tid >> 6, l = tid & 63;
    const int wr = wv >> 1, wc = wv & 1;
    const int rr = l & 15, kb = l >> 4;

    f32x4 acc[4][4];
    #pragma unroll
    for (int i = 0; i < 4; ++i)
        #pragma unroll
        for (int j = 0; j < 4; ++j) acc[i][j] = (f32x4)0.f;

    const int sr = tid >> 2, q = tid & 3;

    for (int kt = 0; kt < 32; ++kt) {
        const int k0 = kt * 32;
        __syncthreads();
        #pragma unroll
        for (int p = 0; p < 2; ++p) {
            const int r = sr + p * 64;
            const int ws = (q ^ ((r >> 1) & 3)) << 3;       // ushort offset
            const size_t ga = (size_t)(m0 + r) * HIDDEN + k0 + q * 8;
            const size_t gb = (size_t)(n0 + r) * HIDDEN + k0 + q * 8;
            *(short8*)&sAh[r*32 + ws] = *(const short8*)(Ahp + ga);
            *(short8*)&sAl[r*32 + ws] = *(const short8*)(Alp + ga);
            *(short8*)&sBh[r*32 + ws] = *(const short8*)(Bhp + gb);
            *(short8*)&sBl[r*32 + ws] = *(const short8*)(Blp + gb);
        }
        __syncthreads();

        short8 fah[4], fal[4], fbh[4], fbl[4];
        #pragma unroll
        for (int i = 0; i < 4; ++i) {
            const int ra = wr*64 + i*16 + rr;
            const int sa = ra*32 + ((kb ^ ((ra >> 1) & 3)) << 3);
            fah[i] = *(const short8*)&sAh[sa];
            fal[i] = *(const short8*)&sAl[sa];
            const int rb = wc*64 + i*16 + rr;
            const int sb = rb*32 + ((kb ^ ((rb >> 1) & 3)) << 3);
            fbh[i] = *(const short8*)&sBh[sb];
            fbl[i] = *(const short8*)&sBl[sb];
        }
        #pragma unroll
        for (int i = 0; i < 4; ++i)
            #pragma unroll
            for (int j = 0; j < 4; ++j) {
                acc[i][j] = __builtin_amdgcn_mfma_f32_16x16x32_bf16(fah[i], fbh[j], acc[i][j], 0, 0, 0);
                acc[i][j] = __builtin_amdgcn_mfma_f32_16x16x32_bf16(fah[i], fbl[j], acc[i][j], 0, 0, 0);
                acc[i][j] = __builtin_amdgcn_mfma_f32_16x16x32_bf16(fal[i], fbh[j], acc[i][j], 0, 0, 0);
            }
    }

    #pragma unroll
    for (int j = 0; j < 4; ++j) {
        const int col = n0 + wc*64 + j*16 + rr;
        const float bj = bout[col];
        #pragma unroll
        for (int i = 0; i < 4; ++i) {
            const int row0 = m0 + wr*64 + i*16 + kb*4;
            #pragma unroll
            for (int p = 0; p < 4; ++p)
                out[(size_t)(row0 + p) * VOCAB + col] = acc[i][j][p] + bj;
        }
    }
}

// ------------------------------------------------- fallback f32 logits GEMM
__global__ __launch_bounds__(256) void k_logits(
    const float* __restrict__ hs, const float* __restrict__ Wout,
    const float* __restrict__ bout, float* __restrict__ out)
{
    __shared__ float At[16][132];
    __shared__ float Bt[16][132];
    const int col0 = blockIdx.x * 128;
    const int row0 = blockIdx.y * 128;
    const int tid = threadIdx.x;
    const int tx = tid & 15, ty = tid >> 4;

    float acc[8][8] = {};

    for (int k0 = 0; k0 < HIDDEN; k0 += 16) {
        float4 av[2], bv[2];
        #pragma unroll
        for (int p = 0; p < 2; ++p) {
            const int idx = tid + p * 256;
            const int m = idx >> 2, qq = idx & 3;
            av[p] = *(const float4*)(hs + (size_t)(row0 + m) * HIDDEN + k0 + qq * 4);
            const int n4 = idx & 31, kk = idx >> 5;
            bv[p] = *(const float4*)(Wout + (size_t)(k0 + kk) * VOCAB + col0 + n4 * 4);
        }
        __syncthreads();
        #pragma unroll
        for (int p = 0; p < 2; ++p) {
            const int idx = tid + p * 256;
            const int m = idx >> 2, qq = idx & 3;
            At[qq*4+0][m] = av[p].x; At[qq*4+1][m] = av[p].y;
            At[qq*4+2][m] = av[p].z; At[qq*4+3][m] = av[p].w;
            const int n4 = idx & 31, kk = idx >> 5;
            *(float4*)&Bt[kk][n4*4] = bv[p];
        }
        __syncthreads();

        #pragma unroll
        for (int k = 0; k < 16; ++k) {
            float a[8], b[8];
            *(float4*)&a[0] = *(const float4*)&At[k][ty*4];
            *(float4*)&a[4] = *(const float4*)&At[k][64 + ty*4];
            *(float4*)&b[0] = *(const float4*)&Bt[k][tx*4];
            *(float4*)&b[4] = *(const float4*)&Bt[k][64 + tx*4];
            #pragma unroll
            for (int i = 0; i < 8; ++i)
                #pragma unroll
                for (int j = 0; j < 8; ++j)
                    acc[i][j] = fmaf(a[i], b[j], acc[i][j]);
        }
    }

    const float4 blo = *(const float4*)(bout + col0 + tx*4);
    const float4 bhi = *(const float4*)(bout + col0 + 64 + tx*4);
    #pragma unroll
    for (int ih = 0; ih < 2; ++ih)
        #pragma unroll
        for (int i = 0; i < 4; ++i) {
            const int row = row0 + ih*64 + ty*4 + i;
            float* orow = out + (size_t)row * VOCAB + col0;
            const int r = ih*4 + i;
            float4 v0 = make_float4(acc[r][0] + blo.x, acc[r][1] + blo.y,
                                    acc[r][2] + blo.z, acc[r][3] + blo.w);
            float4 v1 = make_float4(acc[r][4] + bhi.x, acc[r][5] + bhi.y,
                                    acc[r][6] + bhi.z, acc[r][7] + bhi.w);
            *(float4*)(orow + tx*4) = v0;
            *(float4*)(orow + 64 + tx*4) = v1;
        }
}

// ----------------------------------------------------------------- launch
extern "C" void kernel_launch(void* const* d_in, const int* in_sizes, int n_in,
                              void* d_out, int out_size, void* d_ws, size_t ws_size,
                              hipStream_t stream) {
    const int*   tok  = (const int*)d_in[0];
    const float* emb  = (const float*)d_in[1];
    const float* Wxh  = (const float*)d_in[2];
    const float* Whh  = (const float*)d_in[3];
    const float* bias = (const float*)d_in[4];
    const float* Wout = (const float*)d_in[5];
    const float* bout = (const float*)d_in[6];
    float* out = (float*)d_out;

    char* ws = (char*)d_ws;
    int* flags = (int*)ws;

    // layout (bytes); first 64 KB = flag region
    const size_t OFF_HS   = 65536;
    const size_t OFF_HSH  = OFF_HS  + (size_t)M_TOTAL * HIDDEN * 4;
    const size_t OFF_HSL  = OFF_HSH + (size_t)M_TOTAL * HIDDEN * 2;
    const size_t OFF_WTH  = OFF_HSL + (size_t)M_TOTAL * HIDDEN * 2;
    const size_t OFF_WTL  = OFF_WTH + (size_t)VOCAB * HIDDEN * 2;
    const size_t OFF_XP   = OFF_WTL + (size_t)VOCAB * HIDDEN * 2;
    const size_t NEED     = OFF_XP  + (size_t)M_TOTAL * HIDDEN * 4;

    if (ws_size >= NEED) {
        float*          hs   = (float*)(ws + OFF_HS);
        unsigned short* hsh  = (unsigned short*)(ws + OFF_HSH);
        unsigned short* hsl  = (unsigned short*)(ws + OFF_HSL);
        unsigned short* wth  = (unsigned short*)(ws + OFF_WTH);
        unsigned short* wtl  = (unsigned short*)(ws + OFF_WTL);
        float*          xproj= (float*)(ws + OFF_XP);

        hipLaunchKernelGGL(k_zero, dim3(64), dim3(256), 0, stream, flags);
        hipLaunchKernelGGL(k_embed_xproj, dim3(HIDDEN/64, M_TOTAL/64), dim3(256), 0, stream,
                           tok, emb, Wxh, bias, xproj);
        hipLaunchKernelGGL(k_rnn, dim3(RNN_BLOCKS + CONVBLKS), dim3(256), 0, stream,
                           xproj, Whh, hs, flags, hsh, hsl, Wout, wth, wtl);
        hipLaunchKernelGGL(k_logits_mfma, dim3((VOCAB/128)*(M_TOTAL/128)), dim3(256), 0, stream,
                           hsh, hsl, wth, wtl, bout, out);
    } else {
        // fallback: f32 logits path (fits in ~33 MB); no conv blocks
        float* xproj = (float*)(ws + 65536);
        float* hs    = (float*)(ws + 65536 + (size_t)M_TOTAL * HIDDEN * 4);

        hipLaunchKernelGGL(k_zero, dim3(64), dim3(256), 0, stream, flags);
        hipLaunchKernelGGL(k_embed_xproj, dim3(HIDDEN/64, M_TOTAL/64), dim3(256), 0, stream,
                           tok, emb, Wxh, bias, xproj);
        hipLaunchKernelGGL(k_rnn, dim3(RNN_BLOCKS), dim3(256), 0, stream,
                           xproj, Whh, hs, flags,
                           (unsigned short*)nullptr, (unsigned short*)nullptr,
                           (const float*)nullptr,
                           (unsigned short*)nullptr, (unsigned short*)nullptr);
        hipLaunchKernelGGL(k_logits, dim3(VOCAB/128, M_TOTAL/128), dim3(256), 0, stream,
                           hs, Wout, bout, out);
    }
}